// Round 1
// baseline (81.264 us; speedup 1.0000x reference)
//
#include <hip/hip_runtime.h>
#include <math.h>

#define DIM 4194304
#define N4 (DIM / 4)
#define RBLOCKS 1024
#define RTHREADS 256
#define EPSF 1e-24f

// ---------------- Kernel 1: block-partial sums of ||g||^2 and ||xc-xp||^2 ----------------
__global__ __launch_bounds__(RTHREADS) void k_reduce(const float* __restrict__ grad,
                                                     const float* __restrict__ xp,
                                                     const float* __restrict__ xc,
                                                     float* __restrict__ partials) {
    const float4* g4 = reinterpret_cast<const float4*>(grad);
    const float4* p4 = reinterpret_cast<const float4*>(xp);
    const float4* c4 = reinterpret_cast<const float4*>(xc);
    int tid = blockIdx.x * RTHREADS + threadIdx.x;
    float sg = 0.f, sm = 0.f;
    constexpr int STRIDE = RBLOCKS * RTHREADS;
    constexpr int ITERS = N4 / STRIDE;  // 1048576 / 262144 = 4
#pragma unroll
    for (int it = 0; it < ITERS; ++it) {
        int i = tid + it * STRIDE;
        float4 gv = g4[i];
        float4 pv = p4[i];
        float4 cv = c4[i];
        sg += gv.x * gv.x + gv.y * gv.y + gv.z * gv.z + gv.w * gv.w;
        float mx = cv.x - pv.x, my = cv.y - pv.y, mz = cv.z - pv.z, mw = cv.w - pv.w;
        sm += mx * mx + my * my + mz * mz + mw * mw;
    }
    // wave(64) reduce, then cross-wave via LDS — fixed order => deterministic
#pragma unroll
    for (int off = 32; off > 0; off >>= 1) {
        sg += __shfl_down(sg, off);
        sm += __shfl_down(sm, off);
    }
    __shared__ float wg[4], wm[4];
    int wave = threadIdx.x >> 6;
    if ((threadIdx.x & 63) == 0) {
        wg[wave] = sg;
        wm[wave] = sm;
    }
    __syncthreads();
    if (threadIdx.x == 0) {
        partials[2 * blockIdx.x]     = wg[0] + wg[1] + wg[2] + wg[3];
        partials[2 * blockIdx.x + 1] = wm[0] + wm[1] + wm[2] + wm[3];
    }
}

// ---------------- Kernel 2: finish reduction, scalar MLP, weight pre-composition ----------------
__global__ __launch_bounds__(64) void k_scalar(const float* __restrict__ partials,
                                               const float* __restrict__ loss_curr,
                                               const float* __restrict__ loss_prev,
                                               const float* __restrict__ Wc1,
                                               const float* __restrict__ Wc2,
                                               const float* __restrict__ Wc3,
                                               const float* __restrict__ Wc4,
                                               const float* __restrict__ Wc5,
                                               const float* __restrict__ Wc6,
                                               const float* __restrict__ Wc7,
                                               const float* __restrict__ Wl1,
                                               const float* __restrict__ Wl2,
                                               const float* __restrict__ Wl3,
                                               const float* __restrict__ Wl4,
                                               const float* __restrict__ Wl5,
                                               float* __restrict__ params) {
    int lane = threadIdx.x;
    float sg = 0.f, sm = 0.f;
    for (int i = lane; i < RBLOCKS; i += 64) {
        sg += partials[2 * i];
        sm += partials[2 * i + 1];
    }
#pragma unroll
    for (int off = 32; off > 0; off >>= 1) {
        sg += __shfl_down(sg, off);
        sm += __shfl_down(sm, off);
    }
    if (lane == 0) {
        float g_norm = sqrtf(sg), m_norm = sqrtf(sm);
        float g_inv = (g_norm > EPSF) ? 1.f / g_norm : 1.f;
        float m_inv = (m_norm > EPSF) ? 1.f / m_norm : 1.f;
        // coefficients MLP: 4 -> 8 -> 8 -> 8 -> 8 -> 1
        float feats[4] = {log1pf(g_norm), log1pf(m_norm), log1pf(loss_curr[0]), log1pf(loss_prev[0])};
        float h1[8], h2[8], h3[8], h4[8];
#pragma unroll
        for (int o = 0; o < 8; ++o) {
            float a = 0.f;
            for (int i = 0; i < 4; ++i) a += Wl1[o * 4 + i] * feats[i];
            h1[o] = fmaxf(a, 0.f);
        }
#pragma unroll
        for (int o = 0; o < 8; ++o) {
            float a = 0.f;
            for (int i = 0; i < 8; ++i) a += Wl2[o * 8 + i] * h1[i];
            h2[o] = fmaxf(a, 0.f);
        }
#pragma unroll
        for (int o = 0; o < 8; ++o) {
            float a = 0.f;
            for (int i = 0; i < 8; ++i) a += Wl3[o * 8 + i] * h2[i];
            h3[o] = fmaxf(a, 0.f);
        }
#pragma unroll
        for (int o = 0; o < 8; ++o) {
            float a = 0.f;
            for (int i = 0; i < 8; ++i) a += Wl4[o * 8 + i] * h3[i];
            h4[o] = a;  // no relu
        }
        float step = 0.f;
        for (int i = 0; i < 8; ++i) step += Wl5[i] * h4[i];
        params[0] = g_inv;
        params[1] = m_inv;
        params[2] = step;
    }
    // Wc21 = Wc2 @ Wc1  (10x3) — lanes 0..29, entry o*3+i
    if (lane < 30) {
        int o = lane / 3, i = lane % 3;
        float a = 0.f;
        for (int k = 0; k < 10; ++k) a += Wc2[o * 10 + k] * Wc1[k * 3 + i];
        params[3 + lane] = a;
    }
    // w67[i] = sum_k Wc7[k] * Wc6[k][i]  (1x10) — lanes 32..41
    if (lane >= 32 && lane < 42) {
        int i = lane - 32;
        float a = 0.f;
        for (int k = 0; k < 10; ++k) a += Wc7[k] * Wc6[k * 10 + i];
        params[333 + i] = a;
    }
    // copy Wc3, Wc4, Wc5 into the packed params block
    for (int idx = lane; idx < 300; idx += 64) {
        float v = (idx < 100) ? Wc3[idx] : (idx < 200 ? Wc4[idx - 100] : Wc5[idx - 200]);
        params[33 + idx] = v;
    }
}

// ---------------- Kernel 3: per-element direction network + output ----------------
__global__ __launch_bounds__(256) void k_main(const float* __restrict__ grad,
                                              const float* __restrict__ xp,
                                              const float* __restrict__ xc,
                                              const float* __restrict__ params,
                                              float* __restrict__ out) {
    __shared__ float P[343];
    for (int i = threadIdx.x; i < 343; i += 256) P[i] = params[i];
    __syncthreads();
    const float g_inv = P[0], m_inv = P[1], step = P[2];
    const float* W21 = P + 3;    // [10][3]
    const float* W3  = P + 33;   // [10][10]
    const float* W4  = P + 133;  // [10][10]
    const float* W5  = P + 233;  // [10][10]
    const float* w67 = P + 333;  // [10]

    int gid = blockIdx.x * 256 + threadIdx.x;
    float4 gv = reinterpret_cast<const float4*>(grad)[gid];
    float4 pv = reinterpret_cast<const float4*>(xp)[gid];
    float4 cv = reinterpret_cast<const float4*>(xc)[gid];

    float G[4] = {gv.x * g_inv, gv.y * g_inv, gv.z * g_inv, gv.w * g_inv};
    float M[4] = {(cv.x - pv.x) * m_inv, (cv.y - pv.y) * m_inv, (cv.z - pv.z) * m_inv,
                  (cv.w - pv.w) * m_inv};
    float GM[4] = {G[0] * M[0], G[1] * M[1], G[2] * M[2], G[3] * M[3]};

    float t[4][10], u[4][10];

    // layer A: t = relu(W21 @ [g, m, g*m])
#pragma unroll
    for (int c = 0; c < 10; ++c) {
        float w0 = W21[c * 3], w1 = W21[c * 3 + 1], w2 = W21[c * 3 + 2];
#pragma unroll
        for (int e = 0; e < 4; ++e)
            t[e][c] = fmaxf(w0 * G[e] + w1 * M[e] + w2 * GM[e], 0.f);
    }
    // layer B: u = relu(W3 @ t)
#pragma unroll
    for (int c = 0; c < 10; ++c) {
        float a0 = 0.f, a1 = 0.f, a2 = 0.f, a3 = 0.f;
#pragma unroll
        for (int k = 0; k < 10; ++k) {
            float w = W3[c * 10 + k];
            a0 += w * t[0][k];
            a1 += w * t[1][k];
            a2 += w * t[2][k];
            a3 += w * t[3][k];
        }
        u[0][c] = fmaxf(a0, 0.f);
        u[1][c] = fmaxf(a1, 0.f);
        u[2][c] = fmaxf(a2, 0.f);
        u[3][c] = fmaxf(a3, 0.f);
    }
    // layer C: t = relu(W4 @ u)
#pragma unroll
    for (int c = 0; c < 10; ++c) {
        float a0 = 0.f, a1 = 0.f, a2 = 0.f, a3 = 0.f;
#pragma unroll
        for (int k = 0; k < 10; ++k) {
            float w = W4[c * 10 + k];
            a0 += w * u[0][k];
            a1 += w * u[1][k];
            a2 += w * u[2][k];
            a3 += w * u[3][k];
        }
        t[0][c] = fmaxf(a0, 0.f);
        t[1][c] = fmaxf(a1, 0.f);
        t[2][c] = fmaxf(a2, 0.f);
        t[3][c] = fmaxf(a3, 0.f);
    }
    // layer D: u = relu(W5 @ t)
#pragma unroll
    for (int c = 0; c < 10; ++c) {
        float a0 = 0.f, a1 = 0.f, a2 = 0.f, a3 = 0.f;
#pragma unroll
        for (int k = 0; k < 10; ++k) {
            float w = W5[c * 10 + k];
            a0 += w * t[0][k];
            a1 += w * t[1][k];
            a2 += w * t[2][k];
            a3 += w * t[3][k];
        }
        u[0][c] = fmaxf(a0, 0.f);
        u[1][c] = fmaxf(a1, 0.f);
        u[2][c] = fmaxf(a2, 0.f);
        u[3][c] = fmaxf(a3, 0.f);
    }
    // final: dir = w67 . u  (Wc6, Wc7 composed, no relu between them)
    float d0 = 0.f, d1 = 0.f, d2 = 0.f, d3 = 0.f;
#pragma unroll
    for (int k = 0; k < 10; ++k) {
        float w = w67[k];
        d0 += w * u[0][k];
        d1 += w * u[1][k];
        d2 += w * u[2][k];
        d3 += w * u[3][k];
    }
    float4 ov;
    ov.x = cv.x - step * d0;
    ov.y = cv.y - step * d1;
    ov.z = cv.z - step * d2;
    ov.w = cv.w - step * d3;
    reinterpret_cast<float4*>(out)[gid] = ov;
}

extern "C" void kernel_launch(void* const* d_in, const int* in_sizes, int n_in,
                              void* d_out, int out_size, void* d_ws, size_t ws_size,
                              hipStream_t stream) {
    const float* grad      = (const float*)d_in[0];
    const float* xp        = (const float*)d_in[1];
    const float* xc        = (const float*)d_in[2];
    const float* loss_curr = (const float*)d_in[3];
    const float* loss_prev = (const float*)d_in[4];
    const float* Wc1 = (const float*)d_in[5];
    const float* Wc2 = (const float*)d_in[6];
    const float* Wc3 = (const float*)d_in[7];
    const float* Wc4 = (const float*)d_in[8];
    const float* Wc5 = (const float*)d_in[9];
    const float* Wc6 = (const float*)d_in[10];
    const float* Wc7 = (const float*)d_in[11];
    const float* Wl1 = (const float*)d_in[12];
    const float* Wl2 = (const float*)d_in[13];
    const float* Wl3 = (const float*)d_in[14];
    const float* Wl4 = (const float*)d_in[15];
    const float* Wl5 = (const float*)d_in[16];

    float* ws       = (float*)d_ws;
    float* partials = ws;         // 2 * RBLOCKS floats
    float* params   = ws + 2048;  // 343 floats
    float* out      = (float*)d_out;

    k_reduce<<<RBLOCKS, RTHREADS, 0, stream>>>(grad, xp, xc, partials);
    k_scalar<<<1, 64, 0, stream>>>(partials, loss_curr, loss_prev, Wc1, Wc2, Wc3, Wc4, Wc5,
                                   Wc6, Wc7, Wl1, Wl2, Wl3, Wl4, Wl5, params);
    k_main<<<DIM / 4 / 256, 256, 0, stream>>>(grad, xp, xc, params, out);
}

// Round 3
// 54.628 us; speedup vs baseline: 1.4876x; 1.4876x over previous
//
#include <hip/hip_runtime.h>
#include <math.h>

#define DIM 4194304
#define N4 (DIM / 4)
#define RBLOCKS 1024
#define RTHREADS 256
#define EPSF 1e-24f
#define ACT_SCALE 256.0f

// params layout (float slots)
#define P_W21 3    // 30 fp32 (scaled by ACT_SCALE)
#define P_W3 33    // 50 half2
#define P_W4 83    // 50 half2
#define P_W5 133   // 50 half2
#define P_W67 183  // 5 half2
#define P_TOTAL 188

typedef __fp16 half2v __attribute__((ext_vector_type(2)));

__device__ __forceinline__ half2v pack2(float a, float b) {
    return __builtin_amdgcn_cvt_pkrtz(a, b);
}

__device__ __forceinline__ float fdot2(half2v w, half2v a, float acc) {
#if __has_builtin(__builtin_amdgcn_fdot2)
    return __builtin_amdgcn_fdot2(w, a, acc, false);
#else
    return acc + (float)w.x * (float)a.x + (float)w.y * (float)a.y;
#endif
}

// ---------------- Kernel 1: block-partial sums of ||g||^2 and ||xc-xp||^2 ----------------
__global__ __launch_bounds__(RTHREADS) void k_reduce(const float* __restrict__ grad,
                                                     const float* __restrict__ xp,
                                                     const float* __restrict__ xc,
                                                     float* __restrict__ partials) {
    const float4* g4 = reinterpret_cast<const float4*>(grad);
    const float4* p4 = reinterpret_cast<const float4*>(xp);
    const float4* c4 = reinterpret_cast<const float4*>(xc);
    int tid = blockIdx.x * RTHREADS + threadIdx.x;
    float sg = 0.f, sm = 0.f;
    constexpr int STRIDE = RBLOCKS * RTHREADS;
    constexpr int ITERS = N4 / STRIDE;  // 4
#pragma unroll
    for (int it = 0; it < ITERS; ++it) {
        int i = tid + it * STRIDE;
        float4 gv = g4[i];
        float4 pv = p4[i];
        float4 cv = c4[i];
        sg += gv.x * gv.x + gv.y * gv.y + gv.z * gv.z + gv.w * gv.w;
        float mx = cv.x - pv.x, my = cv.y - pv.y, mz = cv.z - pv.z, mw = cv.w - pv.w;
        sm += mx * mx + my * my + mz * mz + mw * mw;
    }
#pragma unroll
    for (int off = 32; off > 0; off >>= 1) {
        sg += __shfl_down(sg, off);
        sm += __shfl_down(sm, off);
    }
    __shared__ float wg[4], wm[4];
    int wave = threadIdx.x >> 6;
    if ((threadIdx.x & 63) == 0) {
        wg[wave] = sg;
        wm[wave] = sm;
    }
    __syncthreads();
    if (threadIdx.x == 0) {
        partials[2 * blockIdx.x]     = wg[0] + wg[1] + wg[2] + wg[3];
        partials[2 * blockIdx.x + 1] = wm[0] + wm[1] + wm[2] + wm[3];
    }
}

// ---------------- Kernel 2: finish reduction, scalar MLP, weight packing ----------------
__global__ __launch_bounds__(64) void k_scalar(const float* __restrict__ partials,
                                               const float* __restrict__ loss_curr,
                                               const float* __restrict__ loss_prev,
                                               const float* __restrict__ Wc1,
                                               const float* __restrict__ Wc2,
                                               const float* __restrict__ Wc3,
                                               const float* __restrict__ Wc4,
                                               const float* __restrict__ Wc5,
                                               const float* __restrict__ Wc6,
                                               const float* __restrict__ Wc7,
                                               const float* __restrict__ Wl1,
                                               const float* __restrict__ Wl2,
                                               const float* __restrict__ Wl3,
                                               const float* __restrict__ Wl4,
                                               const float* __restrict__ Wl5,
                                               float* __restrict__ params) {
    int lane = threadIdx.x;
    float sg = 0.f, sm = 0.f;
    for (int i = lane; i < RBLOCKS; i += 64) {
        sg += partials[2 * i];
        sm += partials[2 * i + 1];
    }
#pragma unroll
    for (int off = 32; off > 0; off >>= 1) {
        sg += __shfl_down(sg, off);
        sm += __shfl_down(sm, off);
    }
    if (lane == 0) {
        float g_norm = sqrtf(sg), m_norm = sqrtf(sm);
        float g_inv = (g_norm > EPSF) ? 1.f / g_norm : 1.f;
        float m_inv = (m_norm > EPSF) ? 1.f / m_norm : 1.f;
        float feats[4] = {log1pf(g_norm), log1pf(m_norm), log1pf(loss_curr[0]), log1pf(loss_prev[0])};
        float h1[8], h2[8], h3[8], h4[8];
#pragma unroll
        for (int o = 0; o < 8; ++o) {
            float a = 0.f;
            for (int i = 0; i < 4; ++i) a += Wl1[o * 4 + i] * feats[i];
            h1[o] = fmaxf(a, 0.f);
        }
#pragma unroll
        for (int o = 0; o < 8; ++o) {
            float a = 0.f;
            for (int i = 0; i < 8; ++i) a += Wl2[o * 8 + i] * h1[i];
            h2[o] = fmaxf(a, 0.f);
        }
#pragma unroll
        for (int o = 0; o < 8; ++o) {
            float a = 0.f;
            for (int i = 0; i < 8; ++i) a += Wl3[o * 8 + i] * h2[i];
            h3[o] = fmaxf(a, 0.f);
        }
#pragma unroll
        for (int o = 0; o < 8; ++o) {
            float a = 0.f;
            for (int i = 0; i < 8; ++i) a += Wl4[o * 8 + i] * h3[i];
            h4[o] = a;  // no relu
        }
        float step = 0.f;
        for (int i = 0; i < 8; ++i) step += Wl5[i] * h4[i];
        params[0] = g_inv;
        params[1] = m_inv;
        params[2] = step * (1.0f / ACT_SCALE);  // undo the activation scaling here
    }
    // W21 = (Wc2 @ Wc1) * ACT_SCALE  (10x3 fp32) — lanes 0..29
    if (lane < 30) {
        int o = lane / 3, i = lane % 3;
        float a = 0.f;
        for (int k = 0; k < 10; ++k) a += Wc2[o * 10 + k] * Wc1[k * 3 + i];
        params[P_W21 + lane] = a * ACT_SCALE;
    }
    // w67[j] = sum_k Wc7[k] * Wc6[k][j], packed as 5 half2 — lanes 32..36
    if (lane >= 32 && lane < 37) {
        int p = lane - 32;
        float a0 = 0.f, a1 = 0.f;
        for (int k = 0; k < 10; ++k) {
            a0 += Wc7[k] * Wc6[k * 10 + 2 * p];
            a1 += Wc7[k] * Wc6[k * 10 + 2 * p + 1];
        }
        reinterpret_cast<half2v*>(params + P_W67)[p] = pack2(a0, a1);
    }
    // pack W3, W4, W5 as half2 pairs along the input dim
    for (int idx = lane; idx < 150; idx += 64) {
        int layer = idx / 50, r = idx % 50;
        int c = r / 5, pp = r % 5;
        const float* W = (layer == 0) ? Wc3 : ((layer == 1) ? Wc4 : Wc5);
        reinterpret_cast<half2v*>(params + P_W3)[idx] =
            pack2(W[c * 10 + 2 * pp], W[c * 10 + 2 * pp + 1]);
    }
}

// ---------------- hidden 10->10 layer on packed f16 activations ----------------
__device__ __forceinline__ void layer10(const half2v* __restrict__ W,
                                        const half2v in[4][5], half2v outp[4][5]) {
#pragma unroll
    for (int cc = 0; cc < 5; ++cc) {
#pragma unroll
        for (int e = 0; e < 4; ++e) {
            float a0 = 0.f, a1 = 0.f;
#pragma unroll
            for (int p = 0; p < 5; ++p) {
                a0 = fdot2(W[(2 * cc) * 5 + p], in[e][p], a0);
                a1 = fdot2(W[(2 * cc + 1) * 5 + p], in[e][p], a1);
            }
            outp[e][cc] = pack2(fmaxf(a0, 0.f), fmaxf(a1, 0.f));
        }
    }
}

// ---------------- Kernel 3: per-element direction network + output ----------------
__global__ __launch_bounds__(256, 4) void k_main(const float* __restrict__ grad,
                                                 const float* __restrict__ xp,
                                                 const float* __restrict__ xc,
                                                 const float* __restrict__ params,
                                                 float* __restrict__ out) {
    const float g_inv = params[0], m_inv = params[1], step = params[2];
    const float* W21 = params + P_W21;
    const half2v* W3  = reinterpret_cast<const half2v*>(params + P_W3);
    const half2v* W4  = reinterpret_cast<const half2v*>(params + P_W4);
    const half2v* W5  = reinterpret_cast<const half2v*>(params + P_W5);
    const half2v* W67 = reinterpret_cast<const half2v*>(params + P_W67);

    int gid = blockIdx.x * 256 + threadIdx.x;
    float4 gv = reinterpret_cast<const float4*>(grad)[gid];
    float4 pv = reinterpret_cast<const float4*>(xp)[gid];
    float4 cv = reinterpret_cast<const float4*>(xc)[gid];

    float G[4] = {gv.x * g_inv, gv.y * g_inv, gv.z * g_inv, gv.w * g_inv};
    float M[4] = {(cv.x - pv.x) * m_inv, (cv.y - pv.y) * m_inv, (cv.z - pv.z) * m_inv,
                  (cv.w - pv.w) * m_inv};
    float GM[4] = {G[0] * M[0], G[1] * M[1], G[2] * M[2], G[3] * M[3]};

    half2v ta[4][5], tb[4][5];

    // layer A: relu(W21 @ [g, m, g*m]) with ACT_SCALE folded into W21, packed to f16
#pragma unroll
    for (int cc = 0; cc < 5; ++cc) {
        float w00 = W21[(2 * cc) * 3], w01 = W21[(2 * cc) * 3 + 1], w02 = W21[(2 * cc) * 3 + 2];
        float w10 = W21[(2 * cc + 1) * 3], w11 = W21[(2 * cc + 1) * 3 + 1],
              w12 = W21[(2 * cc + 1) * 3 + 2];
#pragma unroll
        for (int e = 0; e < 4; ++e) {
            float a0 = fmaxf(w00 * G[e] + w01 * M[e] + w02 * GM[e], 0.f);
            float a1 = fmaxf(w10 * G[e] + w11 * M[e] + w12 * GM[e], 0.f);
            ta[e][cc] = pack2(a0, a1);
        }
    }

    layer10(W3, ta, tb);
    layer10(W4, tb, ta);
    layer10(W5, ta, tb);

    // final: dir = w67 . u   (Wc6, Wc7 composed; 1/ACT_SCALE folded into step)
    float d[4];
#pragma unroll
    for (int e = 0; e < 4; ++e) {
        float a = 0.f;
#pragma unroll
        for (int p = 0; p < 5; ++p) a = fdot2(W67[p], tb[e][p], a);
        d[e] = a;
    }

    float4 ov;
    ov.x = fmaf(-step, d[0], cv.x);
    ov.y = fmaf(-step, d[1], cv.y);
    ov.z = fmaf(-step, d[2], cv.z);
    ov.w = fmaf(-step, d[3], cv.w);
    reinterpret_cast<float4*>(out)[gid] = ov;
}

extern "C" void kernel_launch(void* const* d_in, const int* in_sizes, int n_in,
                              void* d_out, int out_size, void* d_ws, size_t ws_size,
                              hipStream_t stream) {
    const float* grad      = (const float*)d_in[0];
    const float* xp        = (const float*)d_in[1];
    const float* xc        = (const float*)d_in[2];
    const float* loss_curr = (const float*)d_in[3];
    const float* loss_prev = (const float*)d_in[4];
    const float* Wc1 = (const float*)d_in[5];
    const float* Wc2 = (const float*)d_in[6];
    const float* Wc3 = (const float*)d_in[7];
    const float* Wc4 = (const float*)d_in[8];
    const float* Wc5 = (const float*)d_in[9];
    const float* Wc6 = (const float*)d_in[10];
    const float* Wc7 = (const float*)d_in[11];
    const float* Wl1 = (const float*)d_in[12];
    const float* Wl2 = (const float*)d_in[13];
    const float* Wl3 = (const float*)d_in[14];
    const float* Wl4 = (const float*)d_in[15];
    const float* Wl5 = (const float*)d_in[16];

    float* ws       = (float*)d_ws;
    float* partials = ws;         // 2 * RBLOCKS floats
    float* params   = ws + 2048;  // P_TOTAL floats
    float* out      = (float*)d_out;

    k_reduce<<<RBLOCKS, RTHREADS, 0, stream>>>(grad, xp, xc, partials);
    k_scalar<<<1, 64, 0, stream>>>(partials, loss_curr, loss_prev, Wc1, Wc2, Wc3, Wc4, Wc5,
                                   Wc6, Wc7, Wl1, Wl2, Wl3, Wl4, Wl5, params);
    k_main<<<DIM / 4 / 256, 256, 0, stream>>>(grad, xp, xc, params, out);
}

// Round 4
// 50.737 us; speedup vs baseline: 1.6017x; 1.0767x over previous
//
#include <hip/hip_runtime.h>
#include <math.h>
#include <stdint.h>

#define DIM 4194304
#define N4 (DIM / 4)
#define RBLOCKS 1024
#define RTHREADS 256
#define EPSF 1e-24f
#define SCALE 256.0f  // input scale s == activation scale ACT (so g/m weight cols unscaled)

// params dword layout
//  [0]        f32 step_eff = step / SCALE
//  [1],[2]    dup-f16 (g_inv*SCALE), (m_inv*SCALE)
//  [3..32]    W21dup  (10x3, gm column pre-multiplied by 1/SCALE)
//  [33..132]  W3dup   (10x10)
//  [133..232] W4dup
//  [233..332] W5dup
//  [333..342] w67dup  (Wc7 @ Wc6 composed)
#define P_W21 3
#define P_W3 33
#define P_W4 133
#define P_W5 233
#define P_W67 333

typedef _Float16 h2 __attribute__((ext_vector_type(2)));
typedef __fp16 fp16x2 __attribute__((ext_vector_type(2)));

__device__ __forceinline__ h2 pack2f(float a, float b) {
    fp16x2 r = __builtin_amdgcn_cvt_pkrtz(a, b);
    return __builtin_bit_cast(h2, r);
}
__device__ __forceinline__ uint32_t dup16(float v) {
    fp16x2 r = __builtin_amdgcn_cvt_pkrtz(v, v);
    return __builtin_bit_cast(uint32_t, r);
}
__device__ __forceinline__ h2 asH2(uint32_t u) { return __builtin_bit_cast(h2, u); }
__device__ __forceinline__ h2 fma2(h2 a, h2 b, h2 c) { return __builtin_elementwise_fma(a, b, c); }
__device__ __forceinline__ h2 relu2(h2 a) {
    h2 z = {(_Float16)0.0f, (_Float16)0.0f};
    return __builtin_elementwise_max(a, z);
}

// ---------------- Kernel 1: block-partial sums of ||g||^2 and ||xc-xp||^2 ----------------
__global__ __launch_bounds__(RTHREADS) void k_reduce(const float* __restrict__ grad,
                                                     const float* __restrict__ xp,
                                                     const float* __restrict__ xc,
                                                     float* __restrict__ partials) {
    const float4* g4 = reinterpret_cast<const float4*>(grad);
    const float4* p4 = reinterpret_cast<const float4*>(xp);
    const float4* c4 = reinterpret_cast<const float4*>(xc);
    int tid = blockIdx.x * RTHREADS + threadIdx.x;
    float sg = 0.f, sm = 0.f;
    constexpr int STRIDE = RBLOCKS * RTHREADS;
    constexpr int ITERS = N4 / STRIDE;  // 4
#pragma unroll
    for (int it = 0; it < ITERS; ++it) {
        int i = tid + it * STRIDE;
        float4 gv = g4[i];
        float4 pv = p4[i];
        float4 cv = c4[i];
        sg += gv.x * gv.x + gv.y * gv.y + gv.z * gv.z + gv.w * gv.w;
        float mx = cv.x - pv.x, my = cv.y - pv.y, mz = cv.z - pv.z, mw = cv.w - pv.w;
        sm += mx * mx + my * my + mz * mz + mw * mw;
    }
#pragma unroll
    for (int off = 32; off > 0; off >>= 1) {
        sg += __shfl_down(sg, off);
        sm += __shfl_down(sm, off);
    }
    __shared__ float wg[4], wm[4];
    int wave = threadIdx.x >> 6;
    if ((threadIdx.x & 63) == 0) {
        wg[wave] = sg;
        wm[wave] = sm;
    }
    __syncthreads();
    if (threadIdx.x == 0) {
        partials[2 * blockIdx.x]     = wg[0] + wg[1] + wg[2] + wg[3];
        partials[2 * blockIdx.x + 1] = wm[0] + wm[1] + wm[2] + wm[3];
    }
}

// ---------------- Kernel 2: finish reduction, scalar MLP, dup-f16 weight packing ----------------
__global__ __launch_bounds__(64) void k_scalar(const float* __restrict__ partials,
                                               const float* __restrict__ loss_curr,
                                               const float* __restrict__ loss_prev,
                                               const float* __restrict__ Wc1,
                                               const float* __restrict__ Wc2,
                                               const float* __restrict__ Wc3,
                                               const float* __restrict__ Wc4,
                                               const float* __restrict__ Wc5,
                                               const float* __restrict__ Wc6,
                                               const float* __restrict__ Wc7,
                                               const float* __restrict__ Wl1,
                                               const float* __restrict__ Wl2,
                                               const float* __restrict__ Wl3,
                                               const float* __restrict__ Wl4,
                                               const float* __restrict__ Wl5,
                                               float* __restrict__ params) {
    int lane = threadIdx.x;
    uint32_t* Pu = reinterpret_cast<uint32_t*>(params);
    float sg = 0.f, sm = 0.f;
    for (int i = lane; i < RBLOCKS; i += 64) {
        sg += partials[2 * i];
        sm += partials[2 * i + 1];
    }
#pragma unroll
    for (int off = 32; off > 0; off >>= 1) {
        sg += __shfl_down(sg, off);
        sm += __shfl_down(sm, off);
    }
    if (lane == 0) {
        float g_norm = sqrtf(sg), m_norm = sqrtf(sm);
        float g_inv = (g_norm > EPSF) ? 1.f / g_norm : 1.f;
        float m_inv = (m_norm > EPSF) ? 1.f / m_norm : 1.f;
        float feats[4] = {log1pf(g_norm), log1pf(m_norm), log1pf(loss_curr[0]), log1pf(loss_prev[0])};
        float h1[8], h2_[8], h3[8], h4[8];
#pragma unroll
        for (int o = 0; o < 8; ++o) {
            float a = 0.f;
            for (int i = 0; i < 4; ++i) a += Wl1[o * 4 + i] * feats[i];
            h1[o] = fmaxf(a, 0.f);
        }
#pragma unroll
        for (int o = 0; o < 8; ++o) {
            float a = 0.f;
            for (int i = 0; i < 8; ++i) a += Wl2[o * 8 + i] * h1[i];
            h2_[o] = fmaxf(a, 0.f);
        }
#pragma unroll
        for (int o = 0; o < 8; ++o) {
            float a = 0.f;
            for (int i = 0; i < 8; ++i) a += Wl3[o * 8 + i] * h2_[i];
            h3[o] = fmaxf(a, 0.f);
        }
#pragma unroll
        for (int o = 0; o < 8; ++o) {
            float a = 0.f;
            for (int i = 0; i < 8; ++i) a += Wl4[o * 8 + i] * h3[i];
            h4[o] = a;  // no relu
        }
        float step = 0.f;
        for (int i = 0; i < 8; ++i) step += Wl5[i] * h4[i];
        params[0] = step * (1.0f / SCALE);
        Pu[1] = dup16(g_inv * SCALE);
        Pu[2] = dup16(m_inv * SCALE);
    }
    // W21 = Wc2 @ Wc1 (10x3); gm column scaled by 1/SCALE — lanes 0..29
    if (lane < 30) {
        int o = lane / 3, i = lane % 3;
        float a = 0.f;
        for (int k = 0; k < 10; ++k) a += Wc2[o * 10 + k] * Wc1[k * 3 + i];
        if (i == 2) a *= (1.0f / SCALE);
        Pu[P_W21 + lane] = dup16(a);
    }
    // w67[j] = sum_k Wc7[k] * Wc6[k][j] — lanes 32..41
    if (lane >= 32 && lane < 42) {
        int j = lane - 32;
        float a = 0.f;
        for (int k = 0; k < 10; ++k) a += Wc7[k] * Wc6[k * 10 + j];
        Pu[P_W67 + j] = dup16(a);
    }
    // dup-pack W3, W4, W5 (300 entries)
    for (int idx = lane; idx < 300; idx += 64) {
        int layer = idx / 100, r = idx % 100;
        const float* W = (layer == 0) ? Wc3 : ((layer == 1) ? Wc4 : Wc5);
        Pu[P_W3 + idx] = dup16(W[r]);
    }
}

// ---------------- hidden 10->10 layer on two element-pairs ----------------
__device__ __forceinline__ void layer10(const uint32_t* __restrict__ Wp,
                                        const h2 (&i0)[10], const h2 (&i1)[10],
                                        h2 (&o0)[10], h2 (&o1)[10]) {
#pragma unroll
    for (int c = 0; c < 10; ++c) {
        h2 w = asH2(Wp[c * 10]);
        h2 a0 = w * i0[0];
        h2 a1 = w * i1[0];
#pragma unroll
        for (int k = 1; k < 10; ++k) {
            w = asH2(Wp[c * 10 + k]);
            a0 = fma2(w, i0[k], a0);
            a1 = fma2(w, i1[k], a1);
        }
        o0[c] = relu2(a0);
        o1[c] = relu2(a1);
    }
}

// ---------------- Kernel 3: per-element direction network + output ----------------
__global__ __launch_bounds__(256, 4) void k_main(const float* __restrict__ grad,
                                                 const float* __restrict__ xp,
                                                 const float* __restrict__ xc,
                                                 const float* __restrict__ params,
                                                 float* __restrict__ out) {
    const uint32_t* Pu = reinterpret_cast<const uint32_t*>(params);
    const float step_eff = params[0];
    const h2 gs = asH2(Pu[1]);
    const h2 ms = asH2(Pu[2]);

    int gid = blockIdx.x * 256 + threadIdx.x;
    float4 gv = reinterpret_cast<const float4*>(grad)[gid];
    float4 pv = reinterpret_cast<const float4*>(xp)[gid];
    float4 cv = reinterpret_cast<const float4*>(xc)[gid];

    // packed, pre-scaled inputs: G' = g*g_inv*SCALE, M' = m*m_inv*SCALE, GM' = G'*M'
    h2 G0 = pack2f(gv.x, gv.y) * gs;
    h2 G1 = pack2f(gv.z, gv.w) * gs;
    h2 M0 = pack2f(cv.x - pv.x, cv.y - pv.y) * ms;
    h2 M1 = pack2f(cv.z - pv.z, cv.w - pv.w) * ms;
    h2 GM0 = G0 * M0;
    h2 GM1 = G1 * M1;

    h2 ta0[10], ta1[10], tb0[10], tb1[10];

    // layer A: relu(W21 @ [g, m, g*m])  (gm weight column carries the 1/SCALE)
#pragma unroll
    for (int c = 0; c < 10; ++c) {
        h2 w0 = asH2(Pu[P_W21 + c * 3]);
        h2 w1 = asH2(Pu[P_W21 + c * 3 + 1]);
        h2 w2 = asH2(Pu[P_W21 + c * 3 + 2]);
        ta0[c] = relu2(fma2(w0, G0, fma2(w1, M0, w2 * GM0)));
        ta1[c] = relu2(fma2(w0, G1, fma2(w1, M1, w2 * GM1)));
    }

    layer10(Pu + P_W3, ta0, ta1, tb0, tb1);
    layer10(Pu + P_W4, tb0, tb1, ta0, ta1);
    layer10(Pu + P_W5, ta0, ta1, tb0, tb1);

    // final: dir = w67 . u  (Wc6,Wc7 composed; no relu between them)
    h2 w = asH2(Pu[P_W67]);
    h2 d0 = w * tb0[0];
    h2 d1 = w * tb1[0];
#pragma unroll
    for (int k = 1; k < 10; ++k) {
        w = asH2(Pu[P_W67 + k]);
        d0 = fma2(w, tb0[k], d0);
        d1 = fma2(w, tb1[k], d1);
    }

    float4 ov;
    ov.x = fmaf(-step_eff, (float)d0.x, cv.x);
    ov.y = fmaf(-step_eff, (float)d0.y, cv.y);
    ov.z = fmaf(-step_eff, (float)d1.x, cv.z);
    ov.w = fmaf(-step_eff, (float)d1.y, cv.w);
    reinterpret_cast<float4*>(out)[gid] = ov;
}

extern "C" void kernel_launch(void* const* d_in, const int* in_sizes, int n_in,
                              void* d_out, int out_size, void* d_ws, size_t ws_size,
                              hipStream_t stream) {
    const float* grad      = (const float*)d_in[0];
    const float* xp        = (const float*)d_in[1];
    const float* xc        = (const float*)d_in[2];
    const float* loss_curr = (const float*)d_in[3];
    const float* loss_prev = (const float*)d_in[4];
    const float* Wc1 = (const float*)d_in[5];
    const float* Wc2 = (const float*)d_in[6];
    const float* Wc3 = (const float*)d_in[7];
    const float* Wc4 = (const float*)d_in[8];
    const float* Wc5 = (const float*)d_in[9];
    const float* Wc6 = (const float*)d_in[10];
    const float* Wc7 = (const float*)d_in[11];
    const float* Wl1 = (const float*)d_in[12];
    const float* Wl2 = (const float*)d_in[13];
    const float* Wl3 = (const float*)d_in[14];
    const float* Wl4 = (const float*)d_in[15];
    const float* Wl5 = (const float*)d_in[16];

    float* ws       = (float*)d_ws;
    float* partials = ws;         // 2 * RBLOCKS floats
    float* params   = ws + 2048;  // 343 dwords
    float* out      = (float*)d_out;

    k_reduce<<<RBLOCKS, RTHREADS, 0, stream>>>(grad, xp, xc, partials);
    k_scalar<<<1, 64, 0, stream>>>(partials, loss_curr, loss_prev, Wc1, Wc2, Wc3, Wc4, Wc5,
                                   Wc6, Wc7, Wl1, Wl2, Wl3, Wl4, Wl5, params);
    k_main<<<DIM / 4 / 256, 256, 0, stream>>>(grad, xp, xc, params, out);
}

// Round 5
// 50.539 us; speedup vs baseline: 1.6079x; 1.0039x over previous
//
#include <hip/hip_runtime.h>
#include <math.h>
#include <stdint.h>

#define DIM 4194304
#define N4 (DIM / 4)       // 1048576 float4 per array
#define HALF4 (N4 / 2)     // 524288  — threads in k_main; each does f4 idx t and t+HALF4
#define RBLOCKS 1024
#define RTHREADS 256
#define EPSF 1e-24f
#define SCALE 256.0f

// params dword layout
//  [0]        f32 step_eff = step / SCALE
//  [1],[2]    dup-f16 (g_inv*SCALE), (m_inv*SCALE)
//  [3..32]    W21dup  (10x3, gm column pre-multiplied by 1/SCALE)
//  [33..132]  W3dup   (10x10)
//  [133..232] W4dup
//  [233..332] W5dup
//  [333..342] w67dup  (Wc7 @ Wc6 composed)
#define P_W21 3
#define P_W3 33
#define P_W4 133
#define P_W5 233
#define P_W67 333

typedef _Float16 h2 __attribute__((ext_vector_type(2)));
typedef __fp16 fp16x2 __attribute__((ext_vector_type(2)));
typedef const __attribute__((address_space(4))) uint32_t cu32;  // AMDGPU constant AS -> s_load

__device__ __forceinline__ h2 pack2f(float a, float b) {
    fp16x2 r = __builtin_amdgcn_cvt_pkrtz(a, b);
    return __builtin_bit_cast(h2, r);
}
__device__ __forceinline__ uint32_t dup16(float v) {
    fp16x2 r = __builtin_amdgcn_cvt_pkrtz(v, v);
    return __builtin_bit_cast(uint32_t, r);
}
__device__ __forceinline__ h2 asH2(uint32_t u) { return __builtin_bit_cast(h2, u); }
__device__ __forceinline__ h2 fma2(h2 a, h2 b, h2 c) { return __builtin_elementwise_fma(a, b, c); }
__device__ __forceinline__ h2 relu2(h2 a) {
    h2 z = {(_Float16)0.0f, (_Float16)0.0f};
    return __builtin_elementwise_max(a, z);
}

// ---------------- Kernel 1: block-partial sums of ||g||^2 and ||xc-xp||^2 ----------------
__global__ __launch_bounds__(RTHREADS) void k_reduce(const float* __restrict__ grad,
                                                     const float* __restrict__ xp,
                                                     const float* __restrict__ xc,
                                                     float* __restrict__ partials) {
    const float4* g4 = reinterpret_cast<const float4*>(grad);
    const float4* p4 = reinterpret_cast<const float4*>(xp);
    const float4* c4 = reinterpret_cast<const float4*>(xc);
    int tid = blockIdx.x * RTHREADS + threadIdx.x;
    float sg = 0.f, sm = 0.f;
    constexpr int STRIDE = RBLOCKS * RTHREADS;
    constexpr int ITERS = N4 / STRIDE;  // 4
#pragma unroll
    for (int it = 0; it < ITERS; ++it) {
        int i = tid + it * STRIDE;
        float4 gv = g4[i];
        float4 pv = p4[i];
        float4 cv = c4[i];
        sg += gv.x * gv.x + gv.y * gv.y + gv.z * gv.z + gv.w * gv.w;
        float mx = cv.x - pv.x, my = cv.y - pv.y, mz = cv.z - pv.z, mw = cv.w - pv.w;
        sm += mx * mx + my * my + mz * mz + mw * mw;
    }
#pragma unroll
    for (int off = 32; off > 0; off >>= 1) {
        sg += __shfl_down(sg, off);
        sm += __shfl_down(sm, off);
    }
    __shared__ float wg[4], wm[4];
    int wave = threadIdx.x >> 6;
    if ((threadIdx.x & 63) == 0) {
        wg[wave] = sg;
        wm[wave] = sm;
    }
    __syncthreads();
    if (threadIdx.x == 0) {
        partials[2 * blockIdx.x]     = wg[0] + wg[1] + wg[2] + wg[3];
        partials[2 * blockIdx.x + 1] = wm[0] + wm[1] + wm[2] + wm[3];
    }
}

// ---------------- Kernel 2: finish reduction, scalar MLP, dup-f16 weight packing ----------------
__global__ __launch_bounds__(64) void k_scalar(const float* __restrict__ partials,
                                               const float* __restrict__ loss_curr,
                                               const float* __restrict__ loss_prev,
                                               const float* __restrict__ Wc1,
                                               const float* __restrict__ Wc2,
                                               const float* __restrict__ Wc3,
                                               const float* __restrict__ Wc4,
                                               const float* __restrict__ Wc5,
                                               const float* __restrict__ Wc6,
                                               const float* __restrict__ Wc7,
                                               const float* __restrict__ Wl1,
                                               const float* __restrict__ Wl2,
                                               const float* __restrict__ Wl3,
                                               const float* __restrict__ Wl4,
                                               const float* __restrict__ Wl5,
                                               float* __restrict__ params) {
    int lane = threadIdx.x;
    uint32_t* Pu = reinterpret_cast<uint32_t*>(params);
    float sg = 0.f, sm = 0.f;
    for (int i = lane; i < RBLOCKS; i += 64) {
        sg += partials[2 * i];
        sm += partials[2 * i + 1];
    }
#pragma unroll
    for (int off = 32; off > 0; off >>= 1) {
        sg += __shfl_down(sg, off);
        sm += __shfl_down(sm, off);
    }
    if (lane == 0) {
        float g_norm = sqrtf(sg), m_norm = sqrtf(sm);
        float g_inv = (g_norm > EPSF) ? 1.f / g_norm : 1.f;
        float m_inv = (m_norm > EPSF) ? 1.f / m_norm : 1.f;
        float feats[4] = {log1pf(g_norm), log1pf(m_norm), log1pf(loss_curr[0]), log1pf(loss_prev[0])};
        float h1[8], h2_[8], h3[8], h4[8];
#pragma unroll
        for (int o = 0; o < 8; ++o) {
            float a = 0.f;
            for (int i = 0; i < 4; ++i) a += Wl1[o * 4 + i] * feats[i];
            h1[o] = fmaxf(a, 0.f);
        }
#pragma unroll
        for (int o = 0; o < 8; ++o) {
            float a = 0.f;
            for (int i = 0; i < 8; ++i) a += Wl2[o * 8 + i] * h1[i];
            h2_[o] = fmaxf(a, 0.f);
        }
#pragma unroll
        for (int o = 0; o < 8; ++o) {
            float a = 0.f;
            for (int i = 0; i < 8; ++i) a += Wl3[o * 8 + i] * h2_[i];
            h3[o] = fmaxf(a, 0.f);
        }
#pragma unroll
        for (int o = 0; o < 8; ++o) {
            float a = 0.f;
            for (int i = 0; i < 8; ++i) a += Wl4[o * 8 + i] * h3[i];
            h4[o] = a;  // no relu
        }
        float step = 0.f;
        for (int i = 0; i < 8; ++i) step += Wl5[i] * h4[i];
        params[0] = step * (1.0f / SCALE);
        Pu[1] = dup16(g_inv * SCALE);
        Pu[2] = dup16(m_inv * SCALE);
    }
    // W21 = Wc2 @ Wc1 (10x3); gm column scaled by 1/SCALE — lanes 0..29
    if (lane < 30) {
        int o = lane / 3, i = lane % 3;
        float a = 0.f;
        for (int k = 0; k < 10; ++k) a += Wc2[o * 10 + k] * Wc1[k * 3 + i];
        if (i == 2) a *= (1.0f / SCALE);
        Pu[P_W21 + lane] = dup16(a);
    }
    // w67[j] = sum_k Wc7[k] * Wc6[k][j] — lanes 32..41
    if (lane >= 32 && lane < 42) {
        int j = lane - 32;
        float a = 0.f;
        for (int k = 0; k < 10; ++k) a += Wc7[k] * Wc6[k * 10 + j];
        Pu[P_W67 + j] = dup16(a);
    }
    // dup-pack W3, W4, W5 (300 entries)
    for (int idx = lane; idx < 300; idx += 64) {
        int layer = idx / 100, r = idx % 100;
        const float* W = (layer == 0) ? Wc3 : ((layer == 1) ? Wc4 : Wc5);
        Pu[P_W3 + idx] = dup16(W[r]);
    }
}

// scalar (s_load) weight fetch
__device__ __forceinline__ h2 ldw(cu32* Wp, int idx) { return asH2(Wp[idx]); }

// ---------------- hidden 10->10 layer on NP element-pairs, scalar weights ----------------
__device__ __forceinline__ void layer10(cu32* Wp, const h2 (&in)[4][10], h2 (&outp)[4][10]) {
#pragma unroll
    for (int c = 0; c < 10; ++c) {
        h2 w = ldw(Wp, c * 10);
        h2 a0 = w * in[0][0];
        h2 a1 = w * in[1][0];
        h2 a2 = w * in[2][0];
        h2 a3 = w * in[3][0];
#pragma unroll
        for (int k = 1; k < 10; ++k) {
            w = ldw(Wp, c * 10 + k);
            a0 = fma2(w, in[0][k], a0);
            a1 = fma2(w, in[1][k], a1);
            a2 = fma2(w, in[2][k], a2);
            a3 = fma2(w, in[3][k], a3);
        }
        outp[0][c] = relu2(a0);
        outp[1][c] = relu2(a1);
        outp[2][c] = relu2(a2);
        outp[3][c] = relu2(a3);
    }
}

// ---------------- Kernel 3: 8 elements/thread direction network + output ----------------
__global__ __launch_bounds__(256, 4) void k_main(const float* __restrict__ grad,
                                                 const float* __restrict__ xp,
                                                 const float* __restrict__ xc,
                                                 const float* __restrict__ params,
                                                 float* __restrict__ out) {
    cu32* Pc = (cu32*)params;
    const float step_eff = __builtin_bit_cast(float, (uint32_t)Pc[0]);
    const h2 gs = asH2(Pc[1]);
    const h2 ms = asH2(Pc[2]);

    const float4* g4 = reinterpret_cast<const float4*>(grad);
    const float4* p4 = reinterpret_cast<const float4*>(xp);
    const float4* c4 = reinterpret_cast<const float4*>(xc);

    int t = blockIdx.x * 256 + threadIdx.x;
    int i0 = t, i1 = t + HALF4;

    float4 gv0 = g4[i0], gv1 = g4[i1];
    float4 pv0 = p4[i0], pv1 = p4[i1];
    float4 cv0 = c4[i0], cv1 = c4[i1];

    // packed, pre-scaled inputs per pair p: G' = g*g_inv*SCALE, M' = m*m_inv*SCALE
    h2 G[4], M[4], GM[4];
    G[0] = pack2f(gv0.x, gv0.y) * gs;
    G[1] = pack2f(gv0.z, gv0.w) * gs;
    G[2] = pack2f(gv1.x, gv1.y) * gs;
    G[3] = pack2f(gv1.z, gv1.w) * gs;
    M[0] = pack2f(cv0.x - pv0.x, cv0.y - pv0.y) * ms;
    M[1] = pack2f(cv0.z - pv0.z, cv0.w - pv0.w) * ms;
    M[2] = pack2f(cv1.x - pv1.x, cv1.y - pv1.y) * ms;
    M[3] = pack2f(cv1.z - pv1.z, cv1.w - pv1.w) * ms;
#pragma unroll
    for (int p = 0; p < 4; ++p) GM[p] = G[p] * M[p];

    h2 ta[4][10], tb[4][10];

    // layer A: relu(W21 @ [g, m, g*m])  (gm weight column carries the 1/SCALE)
#pragma unroll
    for (int c = 0; c < 10; ++c) {
        h2 w0 = asH2(Pc[P_W21 + c * 3]);
        h2 w1 = asH2(Pc[P_W21 + c * 3 + 1]);
        h2 w2 = asH2(Pc[P_W21 + c * 3 + 2]);
#pragma unroll
        for (int p = 0; p < 4; ++p)
            ta[p][c] = relu2(fma2(w0, G[p], fma2(w1, M[p], w2 * GM[p])));
    }

    layer10(Pc + P_W3, ta, tb);
    layer10(Pc + P_W4, tb, ta);
    layer10(Pc + P_W5, ta, tb);

    // final: dir = w67 . u  (Wc6,Wc7 composed; no relu between them)
    h2 d[4];
    {
        h2 w = asH2(Pc[P_W67]);
#pragma unroll
        for (int p = 0; p < 4; ++p) d[p] = w * tb[p][0];
#pragma unroll
        for (int k = 1; k < 10; ++k) {
            w = asH2(Pc[P_W67 + k]);
#pragma unroll
            for (int p = 0; p < 4; ++p) d[p] = fma2(w, tb[p][k], d[p]);
        }
    }

    float4 ov0, ov1;
    ov0.x = fmaf(-step_eff, (float)d[0].x, cv0.x);
    ov0.y = fmaf(-step_eff, (float)d[0].y, cv0.y);
    ov0.z = fmaf(-step_eff, (float)d[1].x, cv0.z);
    ov0.w = fmaf(-step_eff, (float)d[1].y, cv0.w);
    ov1.x = fmaf(-step_eff, (float)d[2].x, cv1.x);
    ov1.y = fmaf(-step_eff, (float)d[2].y, cv1.y);
    ov1.z = fmaf(-step_eff, (float)d[3].x, cv1.z);
    ov1.w = fmaf(-step_eff, (float)d[3].y, cv1.w);
    reinterpret_cast<float4*>(out)[i0] = ov0;
    reinterpret_cast<float4*>(out)[i1] = ov1;
}

extern "C" void kernel_launch(void* const* d_in, const int* in_sizes, int n_in,
                              void* d_out, int out_size, void* d_ws, size_t ws_size,
                              hipStream_t stream) {
    const float* grad      = (const float*)d_in[0];
    const float* xp        = (const float*)d_in[1];
    const float* xc        = (const float*)d_in[2];
    const float* loss_curr = (const float*)d_in[3];
    const float* loss_prev = (const float*)d_in[4];
    const float* Wc1 = (const float*)d_in[5];
    const float* Wc2 = (const float*)d_in[6];
    const float* Wc3 = (const float*)d_in[7];
    const float* Wc4 = (const float*)d_in[8];
    const float* Wc5 = (const float*)d_in[9];
    const float* Wc6 = (const float*)d_in[10];
    const float* Wc7 = (const float*)d_in[11];
    const float* Wl1 = (const float*)d_in[12];
    const float* Wl2 = (const float*)d_in[13];
    const float* Wl3 = (const float*)d_in[14];
    const float* Wl4 = (const float*)d_in[15];
    const float* Wl5 = (const float*)d_in[16];

    float* ws       = (float*)d_ws;
    float* partials = ws;         // 2 * RBLOCKS floats
    float* params   = ws + 2048;  // 343 dwords
    float* out      = (float*)d_out;

    k_reduce<<<RBLOCKS, RTHREADS, 0, stream>>>(grad, xp, xc, partials);
    k_scalar<<<1, 64, 0, stream>>>(partials, loss_curr, loss_prev, Wc1, Wc2, Wc3, Wc4, Wc5,
                                   Wc6, Wc7, Wl1, Wl2, Wl3, Wl4, Wl5, params);
    k_main<<<HALF4 / 256, 256, 0, stream>>>(grad, xp, xc, params, out);
}